// Round 14
// baseline (213.348 us; speedup 1.0000x reference)
//
#include <hip/hip_runtime.h>

// Problem constants
#define BB 2
#define TT 2048
#define CC 1024
#define HH 16
#define HS 64
#define FF 4096
#define MTOK 4096  // B*T

typedef __attribute__((ext_vector_type(4))) float f32x4;
typedef __attribute__((ext_vector_type(8))) short short8;

__device__ __forceinline__ unsigned short f2b(float f) {
  // f32 -> bf16 round-to-nearest-even (finite inputs)
  unsigned int u = __builtin_bit_cast(unsigned int, f);
  u += 0x7fffu + ((u >> 16) & 1u);
  return (unsigned short)(u >> 16);
}

__device__ __forceinline__ float fast_exp2(float x) {
#if __has_builtin(__builtin_amdgcn_exp2f)
  return __builtin_amdgcn_exp2f(x);
#else
  return exp2f(x);
#endif
}

// pack two f32 -> {lo,hi} bf16 in one dword (RNE)
__device__ __forceinline__ unsigned int cvt_pk_bf16(float lo, float hi) {
  unsigned int r;
  asm("v_cvt_pk_bf16_f32 %0, %1, %2" : "=v"(r) : "v"(lo), "v"(hi));
  return r;
}

// ---------------- fused cast: x, Wproj, W1, W2 -> bf16 in one launch ----------
// group = 8 contiguous f32. Segments: x 524288 | Wproj 131072 | W1 524288 | W2 524288
__global__ void cast_all_kernel(const float* __restrict__ x,
                                const float* __restrict__ wp,
                                const float* __restrict__ w1,
                                const float* __restrict__ w2,
                                unsigned short* __restrict__ xb,
                                unsigned short* __restrict__ wpb,
                                unsigned short* __restrict__ w1b,
                                unsigned short* __restrict__ w2b) {
  int i = blockIdx.x * 256 + threadIdx.x;
  const float* src;
  unsigned short* dst;
  int off;
  if (i < 524288) {
    src = x; dst = xb; off = i;
  } else if (i < 655360) {
    src = wp; dst = wpb; off = i - 524288;
  } else if (i < 1179648) {
    src = w1; dst = w1b; off = i - 655360;
  } else if (i < 1703936) {
    src = w2; dst = w2b; off = i - 1179648;
  } else {
    return;
  }
  f32x4 a = reinterpret_cast<const f32x4*>(src)[2 * off];
  f32x4 b = reinterpret_cast<const f32x4*>(src)[2 * off + 1];
  short8 o;
  o[0] = (short)f2b(a[0]); o[1] = (short)f2b(a[1]);
  o[2] = (short)f2b(a[2]); o[3] = (short)f2b(a[3]);
  o[4] = (short)f2b(b[0]); o[5] = (short)f2b(b[1]);
  o[6] = (short)f2b(b[2]); o[7] = (short)f2b(b[3]);
  reinterpret_cast<short8*>(dst)[off] = o;
}

// Repack Wq/Wk/Wv (H,C,HS) -> Bt[3072][1024] via coalesced LDS transpose.
// Row n = qkv*1024 + h*64 + d, col c. Scale 1/8 folded into Wq (exact pow2).
__global__ void prep_wqkv_kernel(const float* __restrict__ wq,
                                 const float* __restrict__ wk,
                                 const float* __restrict__ wv,
                                 unsigned short* __restrict__ dst) {
  __shared__ float tile[64][65];
  const int qkv = blockIdx.y >> 4;
  const int h = blockIdx.y & 15;
  const int c0 = blockIdx.x * 64;
  const float* w = (qkv == 0) ? wq : (qkv == 1) ? wk : wv;
  const float scale = (qkv == 0) ? 0.125f : 1.0f;
  const int dd = threadIdx.x & 63;  // d on load, c on store
  const int rr = threadIdx.x >> 6;
  const float* src = w + ((size_t)h * 1024 + c0) * 64;
#pragma unroll
  for (int it = 0; it < 16; ++it) {
    int c = it * 4 + rr;
    tile[c][dd] = src[(size_t)c * 64 + dd];
  }
  __syncthreads();
  unsigned short* dbase = dst + ((size_t)(qkv * 1024 + h * 64)) * 1024 + c0;
#pragma unroll
  for (int it = 0; it < 16; ++it) {
    int d = it * 4 + rr;
    dbase[(size_t)d * 1024 + dd] = f2b(tile[dd][d] * scale);
  }
}

// ---------------- GEMM: C[m][n] = sum_k A[m][k] * Bt[n][k], bf16 in, f32 acc ----
// 128x128 tile, BK=64, 512 threads = 8 waves (2 row-groups x 4 col-groups);
// wave tile 64x32 (acc[4][2]). DEPTH-2 pipelined K-loop, 64KB LDS ->
// 2 blocks/CU (launch_bounds(512,4)) so two blocks' waves co-schedule staging
// and MFMA on each CU. Counted s_waitcnt vmcnt(4); never drains mid-loop.
// Per step: vmcnt(4) | bar | ds_read | lgkmcnt(0)+sched_bar | bar |
// STAGE(t+2 -> cur buf) | MFMA. Second barrier makes buf reuse safe (all
// waves' reads complete before any wave's new gload_lds can land there).
// TILE ORDER (L2): XCD x owns bm strips [x*LBM,(x+1)*LBM); windows of
// LBM bm x 8 bn (bm fastest) keep the resident blocks' strips L2-local.
// EPI: 0=QKV scatter (K/V fragment-packed), 1=proj(+x residual), 2=MLP1(+bias,
// SiLU), 3=MLP2 (outf +=)
template <int EPI>
__global__ __launch_bounds__(512, 4) void gemm_bt(
    const unsigned short* __restrict__ A, const unsigned short* __restrict__ Bt,
    const int K, const int N, const float* __restrict__ bias,
    const float* __restrict__ resid, float* __restrict__ outf,
    unsigned short* __restrict__ outb, unsigned short* __restrict__ qout,
    unsigned short* __restrict__ kout, unsigned short* __restrict__ vout) {
  __shared__ __align__(16) unsigned short ldsA[2][128 * 64];
  __shared__ __align__(16) unsigned short ldsB[2][128 * 64];
  const int tid = threadIdx.x;
  const int lane = tid & 63;
  const int wave = tid >> 6;        // 0..7
  const int g = lane >> 4, l16 = lane & 15;
  const int wr = wave >> 2;         // 0..1 (64-row group)
  const int wc = wave & 3;          // 0..3 (32-col group)

  // L2-aware tile order (see header). Requires gy%8==0 and gx%8==0.
  const int gx = gridDim.x;
  const int gy = gridDim.y;
  const int lid = blockIdx.y * gx + blockIdx.x;
  const int xcd = lid & 7;
  const int ii = lid >> 3;          // index within XCD chunk
  const int LBM = gy >> 3;          // bm strips per XCD
  const int W = LBM * 8;            // window = LBM bm x 8 bn
  const int gwin = ii / W;
  const int jj = ii % W;
  const int bm = xcd * LBM + (jj % LBM);
  const int bn = gwin * 8 + (jj / LBM);

  // staging: per instr, 8 lanes cover one 128B row; chunk permuted by XOR swizzle
  const int srow = lane >> 3;                 // row within 8-row group
  const int schunk = (lane & 7) ^ srow;       // pre-swizzled source chunk

  f32x4 acc[4][2] = {};

  const size_t a_row0 = (size_t)bm * 128;
  const size_t b_row0 = (size_t)bn * 128;

  auto STAGE = [&](int step, int buf) {
    const int kt = step * 64;
#pragma unroll
    for (int i = 0; i < 2; ++i) {
      const int row = (wave * 2 + i) * 8 + srow;
      const unsigned short* ga = A + (a_row0 + row) * K + kt + schunk * 8;
      __builtin_amdgcn_global_load_lds(
          (const __attribute__((address_space(1))) unsigned int*)ga,
          (__attribute__((address_space(3))) unsigned int*)(ldsA[buf] + (wave * 2 + i) * 512),
          16, 0, 0);
      const unsigned short* gb = Bt + (b_row0 + row) * K + kt + schunk * 8;
      __builtin_amdgcn_global_load_lds(
          (const __attribute__((address_space(1))) unsigned int*)gb,
          (__attribute__((address_space(3))) unsigned int*)(ldsB[buf] + (wave * 2 + i) * 512),
          16, 0, 0);
    }
  };

  const int nsteps = K >> 6;  // >= 16 for all our shapes
  STAGE(0, 0);
  STAGE(1, 1);
  for (int t = 0; t < nsteps; ++t) {
    const int cur = t & 1;
    if (t < nsteps - 1) {
      // own stage-t loads (oldest 4) landed; stage t+1's 4 may stay in flight
      asm volatile("s_waitcnt vmcnt(4)" ::: "memory");
    } else {
      asm volatile("s_waitcnt vmcnt(0)" ::: "memory");
    }
    __builtin_amdgcn_s_barrier();
    asm volatile("" ::: "memory");
    const unsigned short* bA = ldsA[cur];
    const unsigned short* bB = ldsB[cur];
    short8 af[4][2], bfr[2][2];
#pragma unroll
    for (int mi = 0; mi < 4; ++mi)
#pragma unroll
      for (int ks = 0; ks < 2; ++ks) {
        int row = wr * 64 + mi * 16 + l16;
        int ch = (ks * 4 + g) ^ (row & 7);
        af[mi][ks] = *reinterpret_cast<const short8*>(&bA[row * 64 + ch * 8]);
      }
#pragma unroll
    for (int ni = 0; ni < 2; ++ni)
#pragma unroll
      for (int ks = 0; ks < 2; ++ks) {
        int row = wc * 32 + ni * 16 + l16;
        int ch = (ks * 4 + g) ^ (row & 7);
        bfr[ni][ks] = *reinterpret_cast<const short8*>(&bB[row * 64 + ch * 8]);
      }
    // all of this wave's reads of buf[cur] complete...
    asm volatile("s_waitcnt lgkmcnt(0)" ::: "memory");
    __builtin_amdgcn_sched_barrier(0);
    // ...and all other waves' too: buf[cur] is now safe to overwrite
    __builtin_amdgcn_s_barrier();
    asm volatile("" ::: "memory");
    if (t + 2 < nsteps) STAGE(t + 2, cur);
    __builtin_amdgcn_s_setprio(1);
#pragma unroll
    for (int ks = 0; ks < 2; ++ks)
#pragma unroll
      for (int mi = 0; mi < 4; ++mi)
#pragma unroll
        for (int ni = 0; ni < 2; ++ni)
          acc[mi][ni] = __builtin_amdgcn_mfma_f32_16x16x32_bf16(
              af[mi][ks], bfr[ni][ks], acc[mi][ni], 0, 0, 0);
    __builtin_amdgcn_s_setprio(0);
  }

#pragma unroll
  for (int mi = 0; mi < 4; ++mi) {
#pragma unroll
    for (int ni = 0; ni < 2; ++ni) {
#pragma unroll
      for (int j = 0; j < 4; ++j) {
        const int row = bm * 128 + wr * 64 + mi * 16 + g * 4 + j;
        const int col = bn * 128 + wc * 32 + ni * 16 + l16;
        float v = acc[mi][ni][j];
        if (EPI == 0) {
          int qkv = col >> 10;
          int hd = col & 1023;
          int h = hd >> 6, d = hd & 63;
          int b = row >> 11, t = row & 2047;
          size_t base = (size_t)(b * HH + h) * (TT * HS);
          if (qkv == 0) {
            qout[base + ((size_t)t << 6) + d] = f2b(v);  // row-major [T][HS]
          } else if (qkv == 1) {
            // K fragment-pack: block = (t>>4)*2 + (d>>5), halfword
            // lane*8+e with lane = ((d>>3)&3)*16 + (t&15), e = d&7
            size_t off = ((size_t)((t >> 4) * 2 + (d >> 5)) << 9) +
                         ((((d >> 3) & 3) * 16 + (t & 15)) << 3) + (d & 7);
            kout[base + off] = f2b(v);
          } else {
            // V fragment-pack (transposed): block = (t>>6)*8 + (d>>4)*2 +
            // ((t&63)>>5), lane = ((t>>3)&3)*16 + (d&15), e = t&7
            size_t off = ((size_t)((t >> 6) * 8 + ((d >> 4) << 1) + ((t & 63) >> 5)) << 9) +
                         ((((t >> 3) & 3) * 16 + (d & 15)) << 3) + (t & 7);
            vout[base + off] = f2b(v);
          }
        } else if (EPI == 1) {
          size_t idx = (size_t)row * N + col;
          float r = resid[idx] + v;
          outf[idx] = r;
          outb[idx] = f2b(r);
        } else if (EPI == 2) {
          float pre = v + bias[col];
          float sg = 1.0f / (1.0f + __expf(-pre));
          outb[(size_t)row * N + col] = f2b(pre * sg);
        } else {
          size_t idx = (size_t)row * N + col;
          outf[idx] += v;
        }
      }
    }
  }
}

// ---------------- flash attention (causal, balanced, key-split x2, XCD-local) ----
// SWAPPED QK^T: s[ni] = mfma(kf[ni], qf) -> D[row=key][col=q]; per-lane scalar m/l.
// K and V are FRAGMENT-PACKED in global memory (by the QKV epilogue) so every
// kf/vf load is a fully lane-contiguous 1KB dwordx4 (lane i at base+16*i):
//   kf[ni][ks] at kpack + ((kt*4+ni)*2 + ks)*512 + lane*8
//   vf[dn][ks] at vpack + (kt*8 + dn*2 + ks)*512 + lane*8
// XCD pinning: bh = (bid&7)*4 + ((bid>>3)&3). Key-split x2 with LDS merge.
#define PSTRIDE 66  // shorts; 33 dwords -> odd stride, conflict-free b32/b128
__global__ __launch_bounds__(256, 4) void attn_fwd(
    const unsigned short* __restrict__ qg, const unsigned short* __restrict__ kg,
    const unsigned short* __restrict__ vtg, unsigned short* __restrict__ att) {
  __shared__ __align__(16) unsigned short plds[4][16 * PSTRIDE];
  __shared__ float olds[4][16][65];
  __shared__ float mlds[4][16], llds[4][16];
  const int lane = threadIdx.x & 63;
  const int wave = threadIdx.x >> 6;
  const int g = lane >> 4, l16 = lane & 15;
  const int bid = blockIdx.x;
  const int bh = (bid & 7) * 4 + ((bid >> 3) & 3);  // XCD-local head mapping
  const int b = bh >> 4, h = bh & 15;
  const int pi = wave >> 1, split = wave & 1;
  const int pr = (bid >> 5) * 2 + pi;  // pair index 0..63
  const unsigned short* qh = qg + (size_t)bh * (TT * HS);
  const unsigned short* kh = kg + (size_t)bh * (TT * HS);
  const unsigned short* vth = vtg + (size_t)bh * (TT * HS);
  unsigned short* pw = plds[wave];
  const float L2E = 1.4426950408889634f;

  for (int half = 0; half < 2; ++half) {
    const int tile = half ? (127 - pr) : pr;
    const int r0 = tile * 16;

    short8 qf[2];
#pragma unroll
    for (int ks = 0; ks < 2; ++ks)
      qf[ks] = *reinterpret_cast<const short8*>(
          qh + (size_t)(r0 + l16) * 64 + ks * 32 + g * 8);

    f32x4 oacc[4] = {};
    float mrow = -1e30f, lrow = 0.f;  // per-lane scalars: q-row = l16

    const int nkt = (r0 + 79) >> 6;
    for (int kt = split; kt < nkt; kt += 2) {
      const int s0 = kt << 6;
      short8 kf[4][2];
#pragma unroll
      for (int ni = 0; ni < 4; ++ni)
#pragma unroll
        for (int ks = 0; ks < 2; ++ks)
          kf[ni][ks] = *reinterpret_cast<const short8*>(
              kh + (((size_t)(kt * 4 + ni) * 2 + ks) << 9) + lane * 8);
      f32x4 s[4] = {};
      __builtin_amdgcn_s_setprio(1);
#pragma unroll
      for (int ks = 0; ks < 2; ++ks)
#pragma unroll
        for (int ni = 0; ni < 4; ++ni)
          s[ni] = __builtin_amdgcn_mfma_f32_16x16x32_bf16(kf[ni][ks], qf[ks],
                                                          s[ni], 0, 0, 0);
      __builtin_amdgcn_s_setprio(0);
      // V loads issued early: latency overlaps the softmax chain
      short8 vf[4][2];
#pragma unroll
      for (int dn = 0; dn < 4; ++dn)
#pragma unroll
        for (int ks = 0; ks < 2; ++ks)
          vf[dn][ks] = *reinterpret_cast<const short8*>(
              vth + (((size_t)(kt * 8 + dn * 2 + ks)) << 9) + lane * 8);
      if (kt == nkt - 1) {  // diagonal tile: causal mask (key > q)
        const int sq = r0 + l16;
#pragma unroll
        for (int ni = 0; ni < 4; ++ni)
#pragma unroll
          for (int j = 0; j < 4; ++j) {
            int sk = s0 + ni * 16 + g * 4 + j;
            if (sk > sq) s[ni][j] = -1e30f;
          }
      }
      // --- online softmax: in-register row reduce (q = l16) ---
      float t0 = fmaxf(fmaxf(s[0][0], s[0][1]), fmaxf(s[0][2], s[0][3]));
      float t1 = fmaxf(fmaxf(s[1][0], s[1][1]), fmaxf(s[1][2], s[1][3]));
      float t2 = fmaxf(fmaxf(s[2][0], s[2][1]), fmaxf(s[2][2], s[2][3]));
      float t3 = fmaxf(fmaxf(s[3][0], s[3][1]), fmaxf(s[3][2], s[3][3]));
      float cm = fmaxf(fmaxf(t0, t1), fmaxf(t2, t3));
      cm = fmaxf(cm, __shfl_xor(cm, 16));
      cm = fmaxf(cm, __shfl_xor(cm, 32));
      // defer-max (THR=8, ln units)
      if (__any(cm > mrow + 8.0f)) {
        float mnew = fmaxf(mrow, cm);
        float sc = fast_exp2((mrow - mnew) * L2E);
        mrow = mnew;
        lrow *= sc;
#pragma unroll
        for (int j = 0; j < 4; ++j) {
          float scj = __shfl(sc, g * 4 + j);  // oacc rows live at q=g*4+j
#pragma unroll
          for (int dn = 0; dn < 4; ++dn) oacc[dn][j] *= scj;
        }
      }
      const float mL = mrow * L2E;
#pragma unroll
      for (int ni = 0; ni < 4; ++ni)
#pragma unroll
        for (int j = 0; j < 4; ++j)
          s[ni][j] = fast_exp2(__builtin_fmaf(s[ni][j], L2E, -mL));
      float a0 = (s[0][0] + s[0][1]) + (s[0][2] + s[0][3]);
      float a1 = (s[1][0] + s[1][1]) + (s[1][2] + s[1][3]);
      float a2 = (s[2][0] + s[2][1]) + (s[2][2] + s[2][3]);
      float a3 = (s[3][0] + s[3][1]) + (s[3][2] + s[3][3]);
      float ps = (a0 + a1) + (a2 + a3);
      ps += __shfl_xor(ps, 16);
      ps += __shfl_xor(ps, 32);
      lrow += ps;
      // P -> LDS: lane holds P[q=l16][k=ni*16+g*4+{0..3}] -> 8 packed b32 writes
#pragma unroll
      for (int ni = 0; ni < 4; ++ni) {
        unsigned int w0 = cvt_pk_bf16(s[ni][0], s[ni][1]);
        unsigned int w1 = cvt_pk_bf16(s[ni][2], s[ni][3]);
        unsigned int* pd =
            reinterpret_cast<unsigned int*>(&pw[l16 * PSTRIDE + ni * 16 + g * 4]);
        pd[0] = w0;
        pd[1] = w1;
      }
      asm volatile("" ::: "memory");  // keep P writes before A-frag reads
      short8 pa[2];
#pragma unroll
      for (int ks = 0; ks < 2; ++ks)
        pa[ks] = *reinterpret_cast<const short8*>(&pw[l16 * PSTRIDE + ks * 32 + g * 8]);
      __builtin_amdgcn_s_setprio(1);
#pragma unroll
      for (int ks = 0; ks < 2; ++ks)
#pragma unroll
        for (int dn = 0; dn < 4; ++dn)
          oacc[dn] = __builtin_amdgcn_mfma_f32_16x16x32_bf16(pa[ks], vf[dn][ks],
                                                             oacc[dn], 0, 0, 0);
      __builtin_amdgcn_s_setprio(0);
      asm volatile("" ::: "memory");  // keep A-frag reads before next-iter P writes
    }
    // --- cross-wave merge (split 0 <-> 1) via LDS ---
#pragma unroll
    for (int dn = 0; dn < 4; ++dn)
#pragma unroll
      for (int j = 0; j < 4; ++j)
        olds[wave][g * 4 + j][dn * 16 + l16] = oacc[dn][j];
    if (lane < 16) {
      mlds[wave][lane] = mrow;
      llds[wave][lane] = lrow;
    }
    __syncthreads();
    if (split == 0) {
#pragma unroll
      for (int j = 0; j < 4; ++j) {
        const int q = g * 4 + j;
        float mA = mlds[wave][q], lA = llds[wave][q];
        float mB = mlds[wave ^ 1][q], lB = llds[wave ^ 1][q];
        float ms = fmaxf(mA, mB);
        float a = fast_exp2((mA - ms) * L2E);
        float bb = fast_exp2((mB - ms) * L2E);
        float rinv = 1.0f / (lA * a + lB * bb);
        int t = r0 + q;
#pragma unroll
        for (int dn = 0; dn < 4; ++dn) {
          float ob = olds[wave ^ 1][q][dn * 16 + l16];
          float val = (oacc[dn][j] * a + ob * bb) * rinv;
          att[((size_t)(b * TT + t)) * CC + h * 64 + dn * 16 + l16] = f2b(val);
        }
      }
    }
    __syncthreads();  // protect olds before next half overwrites
  }
}

extern "C" void kernel_launch(void* const* d_in, const int* in_sizes, int n_in,
                              void* d_out, int out_size, void* d_ws, size_t ws_size,
                              hipStream_t stream) {
  const float* x = (const float*)d_in[0];
  const float* Wq = (const float*)d_in[1];
  const float* Wk = (const float*)d_in[2];
  const float* Wv = (const float*)d_in[3];
  const float* Wproj = (const float*)d_in[4];
  const float* W1 = (const float*)d_in[5];
  const float* b1 = (const float*)d_in[6];
  const float* W2 = (const float*)d_in[7];
  float* out = (float*)d_out;
  char* ws = (char*)d_ws;
  const size_t MB = 1024 * 1024;
  unsigned short* xb = (unsigned short*)(ws + 0 * MB);      // 8MB  x bf16 [4096][1024]
  unsigned short* wqkvT = (unsigned short*)(ws + 8 * MB);   // 6MB  [3072][1024]
  unsigned short* wprojb = (unsigned short*)(ws + 14 * MB); // 2MB  [1024][1024]
  unsigned short* w1b = (unsigned short*)(ws + 16 * MB);    // 8MB  [4096][1024]
  unsigned short* w2b = (unsigned short*)(ws + 24 * MB);    // 8MB  [1024][4096]
  unsigned short* qb = (unsigned short*)(ws + 32 * MB);     // 8MB  [BH][T][HS]
  unsigned short* kpk = (unsigned short*)(ws + 40 * MB);    // 8MB  K fragment-packed
  unsigned short* vpk = (unsigned short*)(ws + 48 * MB);    // 8MB  V fragment-packed
  unsigned short* att = (unsigned short*)(ws + 64 * MB);    // 8MB  [4096][1024]
  unsigned short* x1b = (unsigned short*)(ws + 72 * MB);    // 8MB  [4096][1024]
  unsigned short* hb = (unsigned short*)(ws + 80 * MB);     // 32MB [4096][4096]

  cast_all_kernel<<<6656, 256, 0, stream>>>(x, Wproj, W1, W2, xb, wprojb, w1b, w2b);
  prep_wqkv_kernel<<<dim3(16, 48), 256, 0, stream>>>(Wq, Wk, Wv, wqkvT);

  // QKV projection: [4096,1024] x [3072,1024]^T ; K/V scattered to fragment pack
  gemm_bt<0><<<dim3(24, 32), 512, 0, stream>>>(xb, wqkvT, 1024, 3072, nullptr,
                                               nullptr, nullptr, nullptr, qb, kpk, vpk);
  attn_fwd<<<1024, 256, 0, stream>>>(qb, kpk, vpk, att);
  // out-proj + residual: writes d_out (f32) and x1b (bf16)
  gemm_bt<1><<<dim3(8, 32), 512, 0, stream>>>(att, wprojb, 1024, 1024, nullptr,
                                              x, out, x1b, nullptr, nullptr, nullptr);
  // MLP1 + SiLU
  gemm_bt<2><<<dim3(32, 32), 512, 0, stream>>>(x1b, w1b, 1024, 4096, b1, nullptr,
                                               nullptr, hb, nullptr, nullptr, nullptr);
  // MLP2 + residual into d_out
  gemm_bt<3><<<dim3(8, 32), 512, 0, stream>>>(hb, w2b, 4096, 1024, nullptr, nullptr,
                                              out, nullptr, nullptr, nullptr, nullptr);
  (void)in_sizes; (void)n_in; (void)out_size; (void)ws_size;
}

// Round 18
// 205.749 us; speedup vs baseline: 1.0369x; 1.0369x over previous
//
#include <hip/hip_runtime.h>

// Problem constants
#define BB 2
#define TT 2048
#define CC 1024
#define HH 16
#define HS 64
#define FF 4096
#define MTOK 4096  // B*T

typedef __attribute__((ext_vector_type(4))) float f32x4;
typedef __attribute__((ext_vector_type(8))) short short8;

__device__ __forceinline__ unsigned short f2b(float f) {
  // f32 -> bf16 round-to-nearest-even (finite inputs)
  unsigned int u = __builtin_bit_cast(unsigned int, f);
  u += 0x7fffu + ((u >> 16) & 1u);
  return (unsigned short)(u >> 16);
}

__device__ __forceinline__ float fast_exp2(float x) {
#if __has_builtin(__builtin_amdgcn_exp2f)
  return __builtin_amdgcn_exp2f(x);
#else
  return exp2f(x);
#endif
}

// pack two f32 -> {lo,hi} bf16 in one dword (RNE)
__device__ __forceinline__ unsigned int cvt_pk_bf16(float lo, float hi) {
  unsigned int r;
  asm("v_cvt_pk_bf16_f32 %0, %1, %2" : "=v"(r) : "v"(lo), "v"(hi));
  return r;
}

// ---------------- fused cast: x, Wproj, W1, W2 -> bf16 in one launch ----------
// group = 8 contiguous f32. Segments: x 524288 | Wproj 131072 | W1 524288 | W2 524288
__global__ void cast_all_kernel(const float* __restrict__ x,
                                const float* __restrict__ wp,
                                const float* __restrict__ w1,
                                const float* __restrict__ w2,
                                unsigned short* __restrict__ xb,
                                unsigned short* __restrict__ wpb,
                                unsigned short* __restrict__ w1b,
                                unsigned short* __restrict__ w2b) {
  int i = blockIdx.x * 256 + threadIdx.x;
  const float* src;
  unsigned short* dst;
  int off;
  if (i < 524288) {
    src = x; dst = xb; off = i;
  } else if (i < 655360) {
    src = wp; dst = wpb; off = i - 524288;
  } else if (i < 1179648) {
    src = w1; dst = w1b; off = i - 655360;
  } else if (i < 1703936) {
    src = w2; dst = w2b; off = i - 1179648;
  } else {
    return;
  }
  f32x4 a = reinterpret_cast<const f32x4*>(src)[2 * off];
  f32x4 b = reinterpret_cast<const f32x4*>(src)[2 * off + 1];
  short8 o;
  o[0] = (short)f2b(a[0]); o[1] = (short)f2b(a[1]);
  o[2] = (short)f2b(a[2]); o[3] = (short)f2b(a[3]);
  o[4] = (short)f2b(b[0]); o[5] = (short)f2b(b[1]);
  o[6] = (short)f2b(b[2]); o[7] = (short)f2b(b[3]);
  reinterpret_cast<short8*>(dst)[off] = o;
}

// Repack Wq/Wk/Wv (H,C,HS) -> Bt[3072][1024] via coalesced LDS transpose.
// Row n = qkv*1024 + h*64 + d, col c. Scale 1/8 folded into Wq (exact pow2).
__global__ void prep_wqkv_kernel(const float* __restrict__ wq,
                                 const float* __restrict__ wk,
                                 const float* __restrict__ wv,
                                 unsigned short* __restrict__ dst) {
  __shared__ float tile[64][65];
  const int qkv = blockIdx.y >> 4;
  const int h = blockIdx.y & 15;
  const int c0 = blockIdx.x * 64;
  const float* w = (qkv == 0) ? wq : (qkv == 1) ? wk : wv;
  const float scale = (qkv == 0) ? 0.125f : 1.0f;
  const int dd = threadIdx.x & 63;  // d on load, c on store
  const int rr = threadIdx.x >> 6;
  const float* src = w + ((size_t)h * 1024 + c0) * 64;
#pragma unroll
  for (int it = 0; it < 16; ++it) {
    int c = it * 4 + rr;
    tile[c][dd] = src[(size_t)c * 64 + dd];
  }
  __syncthreads();
  unsigned short* dbase = dst + ((size_t)(qkv * 1024 + h * 64)) * 1024 + c0;
#pragma unroll
  for (int it = 0; it < 16; ++it) {
    int d = it * 4 + rr;
    dbase[(size_t)d * 1024 + dd] = f2b(tile[dd][d] * scale);
  }
}

// ---------------- GEMM: C[m][n] = sum_k A[m][k] * Bt[n][k], bf16 in, f32 acc ----
// 128x128 tile, BK=64, 512 threads = 8 waves (2 row-groups x 4 col-groups);
// wave tile 64x32 (acc[4][2]). DEPTH-3 pipelined K-loop: 3 LDS buffer pairs,
// STAGE(t+2) issued during step t (per-wave 4 gload_lds per stage), counted
// s_waitcnt vmcnt(4) + raw s_barrier per step. NOTE vmcnt(4), NOT vmcnt(8):
// at the top of step t each wave has 8 outstanding loads (stages t, t+1);
// vmcnt(4) waits for the OLDEST 4 (= stage t). vmcnt(8) is a NO-OP and races
// the first two steps' ds_reads against unlanded gload_lds (the r15-r17 NaN).
// TILE ORDER (L2): XCD x owns bm strips [x*LBM,(x+1)*LBM); within the chunk,
// tiles are ordered in WINDOWS of LBM bm x 8 bn (bm fastest) so the ~32
// concurrently-resident blocks per XCD share LBM A-strips + 8 B-strips whose
// live K-slices stay L2-resident -> each B strip fetched once per XCD.
// EPI: 0=QKV scatter (K/V fragment-packed), 1=proj(+x residual), 2=MLP1(+bias,
// SiLU), 3=MLP2 (outf +=)
template <int EPI>
__global__ __launch_bounds__(512) void gemm_bt(
    const unsigned short* __restrict__ A, const unsigned short* __restrict__ Bt,
    const int K, const int N, const float* __restrict__ bias,
    const float* __restrict__ resid, float* __restrict__ outf,
    unsigned short* __restrict__ outb, unsigned short* __restrict__ qout,
    unsigned short* __restrict__ kout, unsigned short* __restrict__ vout) {
  __shared__ __align__(16) unsigned short ldsA[3][128 * 64];
  __shared__ __align__(16) unsigned short ldsB[3][128 * 64];
  const int tid = threadIdx.x;
  const int lane = tid & 63;
  const int wave = tid >> 6;        // 0..7
  const int g = lane >> 4, l16 = lane & 15;
  const int wr = wave >> 2;         // 0..1 (64-row group)
  const int wc = wave & 3;          // 0..3 (32-col group)

  // L2-aware tile order (see header). Requires gy%8==0.
  const int gx = gridDim.x;
  const int gy = gridDim.y;
  const int lid = blockIdx.y * gx + blockIdx.x;
  const int xcd = lid & 7;
  const int ii = lid >> 3;          // index within XCD chunk
  const int LBM = gy >> 3;          // bm strips per XCD
  const int W = LBM * 8;            // window = LBM bm x 8 bn
  const int gwin = ii / W;
  const int jj = ii % W;
  const int bm = xcd * LBM + (jj % LBM);
  const int bn = gwin * 8 + (jj / LBM);

  // staging: per instr, 8 lanes cover one 128B row; chunk permuted by XOR swizzle
  const int srow = lane >> 3;                 // row within 8-row group
  const int schunk = (lane & 7) ^ srow;       // pre-swizzled source chunk

  f32x4 acc[4][2] = {};

  const size_t a_row0 = (size_t)bm * 128;
  const size_t b_row0 = (size_t)bn * 128;

  auto STAGE = [&](int step, int buf) {
    const int kt = step * 64;
#pragma unroll
    for (int i = 0; i < 2; ++i) {
      const int row = (wave * 2 + i) * 8 + srow;
      const unsigned short* ga = A + (a_row0 + row) * K + kt + schunk * 8;
      __builtin_amdgcn_global_load_lds(
          (const __attribute__((address_space(1))) unsigned int*)ga,
          (__attribute__((address_space(3))) unsigned int*)(ldsA[buf] + (wave * 2 + i) * 512),
          16, 0, 0);
      const unsigned short* gb = Bt + (b_row0 + row) * K + kt + schunk * 8;
      __builtin_amdgcn_global_load_lds(
          (const __attribute__((address_space(1))) unsigned int*)gb,
          (__attribute__((address_space(3))) unsigned int*)(ldsB[buf] + (wave * 2 + i) * 512),
          16, 0, 0);
    }
  };

  const int nsteps = K >> 6;  // >= 16 for all our shapes
  STAGE(0, 0);
  STAGE(1, 1);
  int buf = 0;
  for (int t = 0; t < nsteps; ++t) {
    if (t < nsteps - 1) {
      // own stage-t loads (oldest 4) landed; stage t+1/t+2 may stay in flight
      asm volatile("s_waitcnt vmcnt(4)" ::: "memory");
    } else {
      asm volatile("s_waitcnt vmcnt(0)" ::: "memory");
    }
    __builtin_amdgcn_s_barrier();
    asm volatile("" ::: "memory");
    const unsigned short* bA = ldsA[buf];
    const unsigned short* bB = ldsB[buf];
    short8 af[4][2], bfr[2][2];
#pragma unroll
    for (int mi = 0; mi < 4; ++mi)
#pragma unroll
      for (int ks = 0; ks < 2; ++ks) {
        int row = wr * 64 + mi * 16 + l16;
        int ch = (ks * 4 + g) ^ (row & 7);
        af[mi][ks] = *reinterpret_cast<const short8*>(&bA[row * 64 + ch * 8]);
      }
#pragma unroll
    for (int ni = 0; ni < 2; ++ni)
#pragma unroll
      for (int ks = 0; ks < 2; ++ks) {
        int row = wc * 32 + ni * 16 + l16;
        int ch = (ks * 4 + g) ^ (row & 7);
        bfr[ni][ks] = *reinterpret_cast<const short8*>(&bB[row * 64 + ch * 8]);
      }
    if (t + 2 < nsteps) {
      int nb = buf + 2;
      if (nb >= 3) nb -= 3;
      STAGE(t + 2, nb);
    }
    __builtin_amdgcn_s_setprio(1);
#pragma unroll
    for (int ks = 0; ks < 2; ++ks)
#pragma unroll
      for (int mi = 0; mi < 4; ++mi)
#pragma unroll
        for (int ni = 0; ni < 2; ++ni)
          acc[mi][ni] = __builtin_amdgcn_mfma_f32_16x16x32_bf16(
              af[mi][ks], bfr[ni][ks], acc[mi][ni], 0, 0, 0);
    __builtin_amdgcn_s_setprio(0);
    buf = (buf == 2) ? 0 : buf + 1;
  }

#pragma unroll
  for (int mi = 0; mi < 4; ++mi) {
#pragma unroll
    for (int ni = 0; ni < 2; ++ni) {
#pragma unroll
      for (int j = 0; j < 4; ++j) {
        const int row = bm * 128 + wr * 64 + mi * 16 + g * 4 + j;
        const int col = bn * 128 + wc * 32 + ni * 16 + l16;
        float v = acc[mi][ni][j];
        if (EPI == 0) {
          int qkv = col >> 10;
          int hd = col & 1023;
          int h = hd >> 6, d = hd & 63;
          int b = row >> 11, t = row & 2047;
          size_t base = (size_t)(b * HH + h) * (TT * HS);
          if (qkv == 0) {
            qout[base + ((size_t)t << 6) + d] = f2b(v);  // row-major [T][HS]
          } else if (qkv == 1) {
            // K fragment-pack: block = (t>>4)*2 + (d>>5), halfword
            // lane*8+e with lane = ((d>>3)&3)*16 + (t&15), e = d&7
            size_t off = ((size_t)((t >> 4) * 2 + (d >> 5)) << 9) +
                         ((((d >> 3) & 3) * 16 + (t & 15)) << 3) + (d & 7);
            kout[base + off] = f2b(v);
          } else {
            // V fragment-pack (transposed): block = (t>>6)*8 + (d>>4)*2 +
            // ((t&63)>>5), lane = ((t>>3)&3)*16 + (d&15), e = t&7
            size_t off = ((size_t)((t >> 6) * 8 + ((d >> 4) << 1) + ((t & 63) >> 5)) << 9) +
                         ((((t >> 3) & 3) * 16 + (d & 15)) << 3) + (t & 7);
            vout[base + off] = f2b(v);
          }
        } else if (EPI == 1) {
          size_t idx = (size_t)row * N + col;
          float r = resid[idx] + v;
          outf[idx] = r;
          outb[idx] = f2b(r);
        } else if (EPI == 2) {
          float pre = v + bias[col];
          float sg = 1.0f / (1.0f + __expf(-pre));
          outb[(size_t)row * N + col] = f2b(pre * sg);
        } else {
          size_t idx = (size_t)row * N + col;
          outf[idx] += v;
        }
      }
    }
  }
}

// ---------------- flash attention (causal, balanced, key-split x2, XCD-local) ----
// SWAPPED QK^T: s[ni] = mfma(kf[ni], qf) -> D[row=key][col=q]; per-lane scalar m/l.
// K and V are FRAGMENT-PACKED in global memory (by the QKV epilogue) so every
// kf/vf load is a fully lane-contiguous 1KB dwordx4 (lane i at base+16*i):
//   kf[ni][ks] at kpack + ((kt*4+ni)*2 + ks)*512 + lane*8
//   vf[dn][ks] at vpack + (kt*8 + dn*2 + ks)*512 + lane*8
// XCD pinning: bh = (bid&7)*4 + ((bid>>3)&3). Key-split x2 with LDS merge.
#define PSTRIDE 66  // shorts; 33 dwords -> odd stride, conflict-free b32/b128
__global__ __launch_bounds__(256, 4) void attn_fwd(
    const unsigned short* __restrict__ qg, const unsigned short* __restrict__ kg,
    const unsigned short* __restrict__ vtg, unsigned short* __restrict__ att) {
  __shared__ __align__(16) unsigned short plds[4][16 * PSTRIDE];
  __shared__ float olds[4][16][65];
  __shared__ float mlds[4][16], llds[4][16];
  const int lane = threadIdx.x & 63;
  const int wave = threadIdx.x >> 6;
  const int g = lane >> 4, l16 = lane & 15;
  const int bid = blockIdx.x;
  const int bh = (bid & 7) * 4 + ((bid >> 3) & 3);  // XCD-local head mapping
  const int b = bh >> 4, h = bh & 15;
  const int pi = wave >> 1, split = wave & 1;
  const int pr = (bid >> 5) * 2 + pi;  // pair index 0..63
  const unsigned short* qh = qg + (size_t)bh * (TT * HS);
  const unsigned short* kh = kg + (size_t)bh * (TT * HS);
  const unsigned short* vth = vtg + (size_t)bh * (TT * HS);
  unsigned short* pw = plds[wave];
  const float L2E = 1.4426950408889634f;

  for (int half = 0; half < 2; ++half) {
    const int tile = half ? (127 - pr) : pr;
    const int r0 = tile * 16;

    short8 qf[2];
#pragma unroll
    for (int ks = 0; ks < 2; ++ks)
      qf[ks] = *reinterpret_cast<const short8*>(
          qh + (size_t)(r0 + l16) * 64 + ks * 32 + g * 8);

    f32x4 oacc[4] = {};
    float mrow = -1e30f, lrow = 0.f;  // per-lane scalars: q-row = l16

    const int nkt = (r0 + 79) >> 6;
    for (int kt = split; kt < nkt; kt += 2) {
      const int s0 = kt << 6;
      short8 kf[4][2];
#pragma unroll
      for (int ni = 0; ni < 4; ++ni)
#pragma unroll
        for (int ks = 0; ks < 2; ++ks)
          kf[ni][ks] = *reinterpret_cast<const short8*>(
              kh + (((size_t)(kt * 4 + ni) * 2 + ks) << 9) + lane * 8);
      f32x4 s[4] = {};
      __builtin_amdgcn_s_setprio(1);
#pragma unroll
      for (int ks = 0; ks < 2; ++ks)
#pragma unroll
        for (int ni = 0; ni < 4; ++ni)
          s[ni] = __builtin_amdgcn_mfma_f32_16x16x32_bf16(kf[ni][ks], qf[ks],
                                                          s[ni], 0, 0, 0);
      __builtin_amdgcn_s_setprio(0);
      // V loads issued early: latency overlaps the softmax chain
      short8 vf[4][2];
#pragma unroll
      for (int dn = 0; dn < 4; ++dn)
#pragma unroll
        for (int ks = 0; ks < 2; ++ks)
          vf[dn][ks] = *reinterpret_cast<const short8*>(
              vth + (((size_t)(kt * 8 + dn * 2 + ks)) << 9) + lane * 8);
      if (kt == nkt - 1) {  // diagonal tile: causal mask (key > q)
        const int sq = r0 + l16;
#pragma unroll
        for (int ni = 0; ni < 4; ++ni)
#pragma unroll
          for (int j = 0; j < 4; ++j) {
            int sk = s0 + ni * 16 + g * 4 + j;
            if (sk > sq) s[ni][j] = -1e30f;
          }
      }
      // --- online softmax: in-register row reduce (q = l16) ---
      float t0 = fmaxf(fmaxf(s[0][0], s[0][1]), fmaxf(s[0][2], s[0][3]));
      float t1 = fmaxf(fmaxf(s[1][0], s[1][1]), fmaxf(s[1][2], s[1][3]));
      float t2 = fmaxf(fmaxf(s[2][0], s[2][1]), fmaxf(s[2][2], s[2][3]));
      float t3 = fmaxf(fmaxf(s[3][0], s[3][1]), fmaxf(s[3][2], s[3][3]));
      float cm = fmaxf(fmaxf(t0, t1), fmaxf(t2, t3));
      cm = fmaxf(cm, __shfl_xor(cm, 16));
      cm = fmaxf(cm, __shfl_xor(cm, 32));
      // defer-max (THR=8, ln units)
      if (__any(cm > mrow + 8.0f)) {
        float mnew = fmaxf(mrow, cm);
        float sc = fast_exp2((mrow - mnew) * L2E);
        mrow = mnew;
        lrow *= sc;
#pragma unroll
        for (int j = 0; j < 4; ++j) {
          float scj = __shfl(sc, g * 4 + j);  // oacc rows live at q=g*4+j
#pragma unroll
          for (int dn = 0; dn < 4; ++dn) oacc[dn][j] *= scj;
        }
      }
      const float mL = mrow * L2E;
#pragma unroll
      for (int ni = 0; ni < 4; ++ni)
#pragma unroll
        for (int j = 0; j < 4; ++j)
          s[ni][j] = fast_exp2(__builtin_fmaf(s[ni][j], L2E, -mL));
      float a0 = (s[0][0] + s[0][1]) + (s[0][2] + s[0][3]);
      float a1 = (s[1][0] + s[1][1]) + (s[1][2] + s[1][3]);
      float a2 = (s[2][0] + s[2][1]) + (s[2][2] + s[2][3]);
      float a3 = (s[3][0] + s[3][1]) + (s[3][2] + s[3][3]);
      float ps = (a0 + a1) + (a2 + a3);
      ps += __shfl_xor(ps, 16);
      ps += __shfl_xor(ps, 32);
      lrow += ps;
      // P -> LDS: lane holds P[q=l16][k=ni*16+g*4+{0..3}] -> 8 packed b32 writes
#pragma unroll
      for (int ni = 0; ni < 4; ++ni) {
        unsigned int w0 = cvt_pk_bf16(s[ni][0], s[ni][1]);
        unsigned int w1 = cvt_pk_bf16(s[ni][2], s[ni][3]);
        unsigned int* pd =
            reinterpret_cast<unsigned int*>(&pw[l16 * PSTRIDE + ni * 16 + g * 4]);
        pd[0] = w0;
        pd[1] = w1;
      }
      asm volatile("" ::: "memory");  // keep P writes before A-frag reads
      short8 pa[2];
#pragma unroll
      for (int ks = 0; ks < 2; ++ks)
        pa[ks] = *reinterpret_cast<const short8*>(&pw[l16 * PSTRIDE + ks * 32 + g * 8]);
      __builtin_amdgcn_s_setprio(1);
#pragma unroll
      for (int ks = 0; ks < 2; ++ks)
#pragma unroll
        for (int dn = 0; dn < 4; ++dn)
          oacc[dn] = __builtin_amdgcn_mfma_f32_16x16x32_bf16(pa[ks], vf[dn][ks],
                                                             oacc[dn], 0, 0, 0);
      __builtin_amdgcn_s_setprio(0);
      asm volatile("" ::: "memory");  // keep A-frag reads before next-iter P writes
    }
    // --- cross-wave merge (split 0 <-> 1) via LDS ---
#pragma unroll
    for (int dn = 0; dn < 4; ++dn)
#pragma unroll
      for (int j = 0; j < 4; ++j)
        olds[wave][g * 4 + j][dn * 16 + l16] = oacc[dn][j];
    if (lane < 16) {
      mlds[wave][lane] = mrow;
      llds[wave][lane] = lrow;
    }
    __syncthreads();
    if (split == 0) {
#pragma unroll
      for (int j = 0; j < 4; ++j) {
        const int q = g * 4 + j;
        float mA = mlds[wave][q], lA = llds[wave][q];
        float mB = mlds[wave ^ 1][q], lB = llds[wave ^ 1][q];
        float ms = fmaxf(mA, mB);
        float a = fast_exp2((mA - ms) * L2E);
        float bb = fast_exp2((mB - ms) * L2E);
        float rinv = 1.0f / (lA * a + lB * bb);
        int t = r0 + q;
#pragma unroll
        for (int dn = 0; dn < 4; ++dn) {
          float ob = olds[wave ^ 1][q][dn * 16 + l16];
          float val = (oacc[dn][j] * a + ob * bb) * rinv;
          att[((size_t)(b * TT + t)) * CC + h * 64 + dn * 16 + l16] = f2b(val);
        }
      }
    }
    __syncthreads();  // protect olds before next half overwrites
  }
}

extern "C" void kernel_launch(void* const* d_in, const int* in_sizes, int n_in,
                              void* d_out, int out_size, void* d_ws, size_t ws_size,
                              hipStream_t stream) {
  const float* x = (const float*)d_in[0];
  const float* Wq = (const float*)d_in[1];
  const float* Wk = (const float*)d_in[2];
  const float* Wv = (const float*)d_in[3];
  const float* Wproj = (const float*)d_in[4];
  const float* W1 = (const float*)d_in[5];
  const float* b1 = (const float*)d_in[6];
  const float* W2 = (const float*)d_in[7];
  float* out = (float*)d_out;
  char* ws = (char*)d_ws;
  const size_t MB = 1024 * 1024;
  unsigned short* xb = (unsigned short*)(ws + 0 * MB);
  unsigned short* wqkvT = (unsigned short*)(ws + 8 * MB);
  unsigned short* wprojb = (unsigned short*)(ws + 14 * MB);
  unsigned short* w1b = (unsigned short*)(ws + 16 * MB);
  unsigned short* w2b = (unsigned short*)(ws + 24 * MB);
  unsigned short* qb = (unsigned short*)(ws + 32 * MB);
  unsigned short* kpk = (unsigned short*)(ws + 40 * MB);
  unsigned short* vpk = (unsigned short*)(ws + 48 * MB);
  unsigned short* att = (unsigned short*)(ws + 64 * MB);
  unsigned short* x1b = (unsigned short*)(ws + 72 * MB);
  unsigned short* hb = (unsigned short*)(ws + 80 * MB);

  cast_all_kernel<<<6656, 256, 0, stream>>>(x, Wproj, W1, W2, xb, wprojb, w1b, w2b);
  prep_wqkv_kernel<<<dim3(16, 48), 256, 0, stream>>>(Wq, Wk, Wv, wqkvT);

  // QKV projection: [4096,1024] x [3072,1024]^T ; K/V scattered to fragment pack
  gemm_bt<0><<<dim3(24, 32), 512, 0, stream>>>(xb, wqkvT, 1024, 3072, nullptr,
                                               nullptr, nullptr, nullptr, qb, kpk, vpk);
  attn_fwd<<<1024, 256, 0, stream>>>(qb, kpk, vpk, att);
  // out-proj + residual: writes d_out (f32) and x1b (bf16)
  gemm_bt<1><<<dim3(8, 32), 512, 0, stream>>>(att, wprojb, 1024, 1024, nullptr,
                                              x, out, x1b, nullptr, nullptr, nullptr);
  // MLP1 + SiLU
  gemm_bt<2><<<dim3(32, 32), 512, 0, stream>>>(x1b, w1b, 1024, 4096, b1, nullptr,
                                               nullptr, hb, nullptr, nullptr, nullptr);
  // MLP2 + residual into d_out
  gemm_bt<3><<<dim3(8, 32), 512, 0, stream>>>(hb, w2b, 4096, 1024, nullptr, nullptr,
                                              out, nullptr, nullptr, nullptr, nullptr);
  (void)in_sizes; (void)n_in; (void)out_size; (void)ws_size;
}